// Round 1
// baseline (46.215 us; speedup 1.0000x reference)
//
#include <hip/hip_runtime.h>

#define IMW 512
#define IMH 512

__device__ __forceinline__ void s2(float& a, float& b) {
    float t = fminf(a, b);
    b = fmaxf(a, b);
    a = t;
}

__global__ void __launch_bounds__(256)
median3_kernel(const float* __restrict__ in, float* __restrict__ out, int total) {
    const int stride = gridDim.x * blockDim.x;
    for (int idx = blockIdx.x * blockDim.x + threadIdx.x; idx < total; idx += stride) {
        const int x = idx & (IMW - 1);
        const int y = (idx >> 9) & (IMH - 1);

        float p0, p1, p2, p3, p4, p5, p6, p7, p8;

        if (x > 0 && x < IMW - 1 && y > 0 && y < IMH - 1) {
            // interior fast path: 3 rows of 3 contiguous loads, no predication
            const float* r = in + idx - IMW - 1;
            p0 = r[0]; p1 = r[1]; p2 = r[2];
            r += IMW;
            p3 = r[0]; p4 = r[1]; p5 = r[2];
            r += IMW;
            p6 = r[0]; p7 = r[1]; p8 = r[2];
        } else {
            // boundary: zero padding
            const int plane = idx & ~(IMW * IMH - 1);
            const float* pb = in + plane;
            float v[9];
#pragma unroll
            for (int dy = -1; dy <= 1; ++dy) {
#pragma unroll
                for (int dx = -1; dx <= 1; ++dx) {
                    const int yy = y + dy;
                    const int xx = x + dx;
                    const bool ok = (yy >= 0) & (yy < IMH) & (xx >= 0) & (xx < IMW);
                    v[(dy + 1) * 3 + (dx + 1)] = ok ? pb[yy * IMW + xx] : 0.0f;
                }
            }
            p0 = v[0]; p1 = v[1]; p2 = v[2];
            p3 = v[3]; p4 = v[4]; p5 = v[5];
            p6 = v[6]; p7 = v[7]; p8 = v[8];
        }

        // median-of-9: 19-exchange network (Smith/Paeth), median lands in p4
        s2(p1, p2); s2(p4, p5); s2(p7, p8);
        s2(p0, p1); s2(p3, p4); s2(p6, p7);
        s2(p1, p2); s2(p4, p5); s2(p7, p8);
        s2(p0, p3); s2(p5, p8); s2(p4, p7);
        s2(p3, p6); s2(p1, p4); s2(p2, p5);
        s2(p4, p7); s2(p4, p2); s2(p6, p4);
        s2(p4, p2);

        out[idx] = p4;
    }
}

extern "C" void kernel_launch(void* const* d_in, const int* in_sizes, int n_in,
                              void* d_out, int out_size, void* d_ws, size_t ws_size,
                              hipStream_t stream) {
    const float* x = (const float*)d_in[0];
    float* out = (float*)d_out;
    const int total = in_sizes[0];  // 16*3*512*512 = 12,582,912

    // grid-stride: 2048 blocks x 256 threads (8 blocks/CU on 256 CUs),
    // stride = 524288 = exactly 2 image planes -> each thread keeps the same
    // (y,x) across iterations (boundary branch loop-invariant).
    const int blocks = 2048;
    median3_kernel<<<blocks, 256, 0, stream>>>(x, out, total);
}

// Round 2
// 29.235 us; speedup vs baseline: 1.5808x; 1.5808x over previous
//
#include <hip/hip_runtime.h>

#define IMW 512
#define IMH 512

__device__ __forceinline__ void s2(float& a, float& b) {
    float t = fminf(a, b);
    b = fmaxf(a, b);
    a = t;
}

__device__ __forceinline__ float max3f(float a, float b, float c) {
    return fmaxf(fmaxf(a, b), c);   // fuses to v_max3_f32
}
__device__ __forceinline__ float min3f(float a, float b, float c) {
    return fminf(fminf(a, b), c);   // fuses to v_min3_f32
}
__device__ __forceinline__ float med3f(float a, float b, float c) {
    return __builtin_amdgcn_fmed3f(a, b, c);  // v_med3_f32
}

// Each thread produces one float4 (4 horizontally-adjacent output pixels).
// Needs 6 input columns (x4-1 .. x4+4) x 3 rows. Zero padding at image edges.
__global__ void __launch_bounds__(256)
median3_vec4(const float* __restrict__ in, float* __restrict__ out) {
    // XCD-aware bijective swizzle: 12288 blocks = 8 XCDs x 1536 contiguous
    // blocks each -> vertical row reuse stays inside one XCD's private L2.
    const int bid = (int)blockIdx.x;
    const int wg  = (bid & 7) * 1536 + (bid >> 3);

    const int v    = wg * 256 + (int)threadIdx.x;   // vector index
    const int x4   = (v & 127) << 2;                // 0..508, step 4
    const int y    = (v >> 7) & (IMH - 1);
    const int base = (v >> 16 << 18) + (y << 9) + x4;  // plane*2^18 + y*512 + x4

    const bool has_left  = (x4 > 0);
    const bool has_right = (x4 < IMW - 4);
    const bool has_top   = (y > 0);       // wave-uniform (y uniform per wave)
    const bool has_bot   = (y < IMH - 1);

    float t0, t1, t2, t3, t4, t5;   // top row,   cols x4-1 .. x4+4
    float m0, m1, m2, m3, m4, m5;   // mid row
    float b0, b1, b2, b3, b4, b5;   // bottom row

    {   // middle row (always valid)
        const float* rp = in + base;
        float4 mv = *reinterpret_cast<const float4*>(rp);
        m1 = mv.x; m2 = mv.y; m3 = mv.z; m4 = mv.w;
        m0 = has_left  ? rp[-1] : 0.0f;
        m5 = has_right ? rp[4]  : 0.0f;
    }
    if (has_top) {
        const float* rp = in + base - IMW;
        float4 tv = *reinterpret_cast<const float4*>(rp);
        t1 = tv.x; t2 = tv.y; t3 = tv.z; t4 = tv.w;
        t0 = has_left  ? rp[-1] : 0.0f;
        t5 = has_right ? rp[4]  : 0.0f;
    } else {
        t0 = t1 = t2 = t3 = t4 = t5 = 0.0f;
    }
    if (has_bot) {
        const float* rp = in + base + IMW;
        float4 bv = *reinterpret_cast<const float4*>(rp);
        b1 = bv.x; b2 = bv.y; b3 = bv.z; b4 = bv.w;
        b0 = has_left  ? rp[-1] : 0.0f;
        b5 = has_right ? rp[4]  : 0.0f;
    } else {
        b0 = b1 = b2 = b3 = b4 = b5 = 0.0f;
    }

    // Sort each of the 6 columns: after this t=min, m=med, b=max per column.
    s2(t0, m0); s2(m0, b0); s2(t0, m0);
    s2(t1, m1); s2(m1, b1); s2(t1, m1);
    s2(t2, m2); s2(m2, b2); s2(t2, m2);
    s2(t3, m3); s2(m3, b3); s2(t3, m3);
    s2(t4, m4); s2(m4, b4); s2(t4, m4);
    s2(t5, m5); s2(m5, b5); s2(t5, m5);

    // median9(cols c-1,c,c+1) = med3( max(mins), med(meds), min(maxs) )
    float4 o;
    o.x = med3f(max3f(t0, t1, t2), med3f(m0, m1, m2), min3f(b0, b1, b2));
    o.y = med3f(max3f(t1, t2, t3), med3f(m1, m2, m3), min3f(b1, b2, b3));
    o.z = med3f(max3f(t2, t3, t4), med3f(m2, m3, m4), min3f(b2, b3, b4));
    o.w = med3f(max3f(t3, t4, t5), med3f(m3, m4, m5), min3f(b3, b4, b5));

    *reinterpret_cast<float4*>(out + base) = o;
}

extern "C" void kernel_launch(void* const* d_in, const int* in_sizes, int n_in,
                              void* d_out, int out_size, void* d_ws, size_t ws_size,
                              hipStream_t stream) {
    const float* x = (const float*)d_in[0];
    float* out = (float*)d_out;
    // total = 16*3*512*512 = 12,582,912 floats = 3,145,728 float4 = 12288 blocks x 256
    const int blocks = in_sizes[0] / 4 / 256;
    median3_vec4<<<blocks, 256, 0, stream>>>(x, out);
}

// Round 4
// 22.704 us; speedup vs baseline: 2.0356x; 1.2877x over previous
//
#include <hip/hip_runtime.h>

#define IMW 512
#define IMH 512

typedef float f32x4 __attribute__((ext_vector_type(4)));

__device__ __forceinline__ void s2(float& a, float& b) {
    float t = fminf(a, b);
    b = fmaxf(a, b);
    a = t;
}
__device__ __forceinline__ float max3f(float a, float b, float c) {
    return fmaxf(fmaxf(a, b), c);   // v_max3_f32
}
__device__ __forceinline__ float min3f(float a, float b, float c) {
    return fminf(fminf(a, b), c);   // v_min3_f32
}
__device__ __forceinline__ float med3f(float a, float b, float c) {
    return __builtin_amdgcn_fmed3f(a, b, c);  // v_med3_f32
}

// Each thread produces a 2-row x 4-col output tile. Loads input rows
// y-1..y+2 (4 vec loads + 8 edge scalars), shares the (y,y+1) pair-sort
// between the two vertical triples (5 s2 per column instead of 6).
__global__ void __launch_bounds__(256)
median3_2x4(const float* __restrict__ in, float* __restrict__ out) {
    // 6144 blocks = 8 XCDs x 768 contiguous -> vertical reuse in one L2.
    const int bid = (int)blockIdx.x;
    const int wg  = (bid & 7) * 768 + (bid >> 3);

    const int g     = wg * 256 + (int)threadIdx.x;
    const int xt    = g & 127;           // float4 slot in row
    const int pair  = (g >> 7) & 255;    // row pair 0..255
    const int plane = g >> 15;           // 0..47
    const int y     = pair << 1;         // even row 0..510
    const int x4    = xt << 2;
    const int base  = (plane << 18) + (y << 9) + x4;

    const bool has_left  = (x4 > 0);
    const bool has_right = (x4 < IMW - 4);
    const bool has_top   = (y > 0);        // wave-uniform
    const bool has_bot   = (y < IMH - 2);  // wave-uniform

    // rows: a=y-1, b=y, c=y+1, d=y+2; cols 0..5 = x4-1 .. x4+4
    float a0,a1,a2,a3,a4,a5, b0,b1,b2,b3,b4,b5,
          c0,c1,c2,c3,c4,c5, d0,d1,d2,d3,d4,d5;

    {
        const float* rp = in + base;
        f32x4 v = *reinterpret_cast<const f32x4*>(rp);
        b1=v.x; b2=v.y; b3=v.z; b4=v.w;
        b0 = has_left  ? rp[-1] : 0.0f;
        b5 = has_right ? rp[4]  : 0.0f;
    }
    {
        const float* rp = in + base + IMW;
        f32x4 v = *reinterpret_cast<const f32x4*>(rp);
        c1=v.x; c2=v.y; c3=v.z; c4=v.w;
        c0 = has_left  ? rp[-1] : 0.0f;
        c5 = has_right ? rp[4]  : 0.0f;
    }
    if (has_top) {
        const float* rp = in + base - IMW;
        f32x4 v = *reinterpret_cast<const f32x4*>(rp);
        a1=v.x; a2=v.y; a3=v.z; a4=v.w;
        a0 = has_left  ? rp[-1] : 0.0f;
        a5 = has_right ? rp[4]  : 0.0f;
    } else {
        a0=a1=a2=a3=a4=a5=0.0f;
    }
    if (has_bot) {
        const float* rp = in + base + 2 * IMW;
        f32x4 v = *reinterpret_cast<const f32x4*>(rp);
        d1=v.x; d2=v.y; d3=v.z; d4=v.w;
        d0 = has_left  ? rp[-1] : 0.0f;
        d5 = has_right ? rp[4]  : 0.0f;
    } else {
        d0=d1=d2=d3=d4=d5=0.0f;
    }

    // Per column: shared s2(b,c), then 2 s2 per triple.
    // Top triple  (a,b,c): min=tn, med=tm, max=tx
    // Bot triple  (b,c,d): min=un, med=um, max=ux
    float tn0,tm0,tx0,un0,um0,ux0, tn1,tm1,tx1,un1,um1,ux1,
          tn2,tm2,tx2,un2,um2,ux2, tn3,tm3,tx3,un3,um3,ux3,
          tn4,tm4,tx4,un4,um4,ux4, tn5,tm5,tx5,un5,um5,ux5;

#define COLSORT(A,B,C,D, TN,TM,TX, UN,UM,UX)            \
    {                                                   \
        float bb=B, cc=C;                               \
        s2(bb, cc);            /* shared pair */        \
        float aa=A, p=bb, q=cc;                         \
        s2(aa, p);  s2(p, q);                           \
        TN=aa; TM=p; TX=q;                              \
        float dd=D, r=cc, s=bb;                         \
        s2(r, dd);  s2(s, r);                           \
        UN=s; UM=r; UX=dd;                              \
    }

    COLSORT(a0,b0,c0,d0, tn0,tm0,tx0, un0,um0,ux0)
    COLSORT(a1,b1,c1,d1, tn1,tm1,tx1, un1,um1,ux1)
    COLSORT(a2,b2,c2,d2, tn2,tm2,tx2, un2,um2,ux2)
    COLSORT(a3,b3,c3,d3, tn3,tm3,tx3, un3,um3,ux3)
    COLSORT(a4,b4,c4,d4, tn4,tm4,tx4, un4,um4,ux4)
    COLSORT(a5,b5,c5,d5, tn5,tm5,tx5, un5,um5,ux5)
#undef COLSORT

    f32x4 o0, o1;
    o0.x = med3f(max3f(tn0,tn1,tn2), med3f(tm0,tm1,tm2), min3f(tx0,tx1,tx2));
    o0.y = med3f(max3f(tn1,tn2,tn3), med3f(tm1,tm2,tm3), min3f(tx1,tx2,tx3));
    o0.z = med3f(max3f(tn2,tn3,tn4), med3f(tm2,tm3,tm4), min3f(tx2,tx3,tx4));
    o0.w = med3f(max3f(tn3,tn4,tn5), med3f(tm3,tm4,tm5), min3f(tx3,tx4,tx5));
    o1.x = med3f(max3f(un0,un1,un2), med3f(um0,um1,um2), min3f(ux0,ux1,ux2));
    o1.y = med3f(max3f(un1,un2,un3), med3f(um1,um2,um3), min3f(ux1,ux2,ux3));
    o1.z = med3f(max3f(un2,un3,un4), med3f(um2,um3,um4), min3f(ux2,ux3,ux4));
    o1.w = med3f(max3f(un3,un4,un5), med3f(um3,um4,um5), min3f(ux3,ux4,ux5));

    __builtin_nontemporal_store(o0, reinterpret_cast<f32x4*>(out + base));
    __builtin_nontemporal_store(o1, reinterpret_cast<f32x4*>(out + base + IMW));
}

extern "C" void kernel_launch(void* const* d_in, const int* in_sizes, int n_in,
                              void* d_out, int out_size, void* d_ws, size_t ws_size,
                              hipStream_t stream) {
    const float* x = (const float*)d_in[0];
    float* out = (float*)d_out;
    // 12,582,912 px / 8 px-per-thread / 256 = 6144 blocks
    const int blocks = in_sizes[0] / 8 / 256;
    median3_2x4<<<blocks, 256, 0, stream>>>(x, out);
}

// Round 5
// 21.264 us; speedup vs baseline: 2.1734x; 1.0677x over previous
//
#include <hip/hip_runtime.h>

#define IMW 512
#define IMH 512

typedef float f32x4 __attribute__((ext_vector_type(4)));

__device__ __forceinline__ void s2(float& a, float& b) {
    float t = fminf(a, b);
    b = fmaxf(a, b);
    a = t;
}
__device__ __forceinline__ float max3f(float a, float b, float c) {
    return fmaxf(fmaxf(a, b), c);   // v_max3_f32
}
__device__ __forceinline__ float min3f(float a, float b, float c) {
    return fminf(fminf(a, b), c);   // v_min3_f32
}
__device__ __forceinline__ float med3f(float a, float b, float c) {
    return __builtin_amdgcn_fmed3f(a, b, c);  // v_med3_f32
}

// 4 output rows x 4 cols per thread. Input rows y-1..y+4 (6 rows), cols
// xpix-1..xpix+4 (6 cols). Two shared pair-sorts per column, each feeding
// two vertical triples (2 s2 inserts each) -> 10 s2/column per 4 rows.
__global__ void __launch_bounds__(256)
median3_4x4(const float* __restrict__ in, float* __restrict__ out) {
    // 3072 blocks = 8 XCDs x 384 contiguous -> each XCD owns 6 full planes.
    const int bid = (int)blockIdx.x;
    const int wg  = (bid & 7) * 384 + (bid >> 3);

    const int g     = wg * 256 + (int)threadIdx.x;
    const int xt    = g & 127;           // float4 slot in row
    const int quad  = (g >> 7) & 127;    // row-quad 0..127
    const int plane = g >> 14;           // 0..47
    const int y     = quad << 2;         // 0,4,...,508
    const int xpix  = xt << 2;
    const int base  = (plane << 18) + (y << 9) + xpix;

    const bool has_left  = (xpix > 0);
    const bool has_right = (xpix < IMW - 4);
    const bool has_top   = (y > 0);          // wave-uniform
    const bool has_bot   = (y < IMH - 4);    // wave-uniform

    // rows: A=y-1, B=y, C=y+1, D=y+2, E=y+3, F=y+4; cols 0..5 = xpix-1..xpix+4
    float A0,A1,A2,A3,A4,A5, B0,B1,B2,B3,B4,B5, C0,C1,C2,C3,C4,C5,
          D0,D1,D2,D3,D4,D5, E0,E1,E2,E3,E4,E5, F0,F1,F2,F3,F4,F5;

#define LOADR(P0,P1,P2,P3,P4,P5, RP)                        \
    {                                                       \
        const float* rp_ = (RP);                            \
        f32x4 v = *reinterpret_cast<const f32x4*>(rp_);     \
        P1 = v.x; P2 = v.y; P3 = v.z; P4 = v.w;             \
        P0 = has_left  ? rp_[-1] : 0.0f;                    \
        P5 = has_right ? rp_[4]  : 0.0f;                    \
    }

    LOADR(B0,B1,B2,B3,B4,B5, in + base)
    LOADR(C0,C1,C2,C3,C4,C5, in + base + IMW)
    LOADR(D0,D1,D2,D3,D4,D5, in + base + 2 * IMW)
    LOADR(E0,E1,E2,E3,E4,E5, in + base + 3 * IMW)
    if (has_top) {
        LOADR(A0,A1,A2,A3,A4,A5, in + base - IMW)
    } else {
        A0=A1=A2=A3=A4=A5=0.0f;
    }
    if (has_bot) {
        LOADR(F0,F1,F2,F3,F4,F5, in + base + 4 * IMW)
    } else {
        F0=F1=F2=F3=F4=F5=0.0f;
    }
#undef LOADR

    // Shared pair-sorts per column: (B,C) -> L1/H1, (D,E) -> L2/H2.
    // Originals A (row0 insert), D (row1 insert), C (row2 insert),
    // F (row3 insert) stay live; B, E die here.
    float L10,L11,L12,L13,L14,L15, H10,H11,H12,H13,H14,H15,
          L20,L21,L22,L23,L24,L25, H20,H21,H22,H23,H24,H25;
#define PAIRS(c) \
    L1##c = fminf(B##c, C##c); H1##c = fmaxf(B##c, C##c); \
    L2##c = fminf(D##c, E##c); H2##c = fmaxf(D##c, E##c);
    PAIRS(0) PAIRS(1) PAIRS(2) PAIRS(3) PAIRS(4) PAIRS(5)
#undef PAIRS

    // Insert X below a sorted pair (L,H): sort3 -> (N,M,Xo)
#define INS_BOT(N,M,X, A_,L_,H_) \
    float N = (A_), M = (L_), X = (H_); s2(N, M); s2(M, X);
    // Insert X above a sorted pair (L,H): sort3 -> (N,M,Xo)
#define INS_TOP(N,M,X, L_,H_,F_) \
    float N = (L_), M = (H_), X = (F_); s2(M, X); s2(N, M);

#define MERGE(OUT, N0,M0,X0, N1,M1,X1, N2,M2,X2, N3,M3,X3, N4,M4,X4, N5,M5,X5) \
    OUT.x = med3f(max3f(N0,N1,N2), med3f(M0,M1,M2), min3f(X0,X1,X2)); \
    OUT.y = med3f(max3f(N1,N2,N3), med3f(M1,M2,M3), min3f(X1,X2,X3)); \
    OUT.z = med3f(max3f(N2,N3,N4), med3f(M2,M3,M4), min3f(X2,X3,X4)); \
    OUT.w = med3f(max3f(N3,N4,N5), med3f(M3,M4,M5), min3f(X3,X4,X5));

    f32x4 o;
    {   // row 0: triple (A,B,C) = insert A into (L1,H1)
        INS_BOT(n0,m0,x0, A0,L10,H10) INS_BOT(n1,m1,x1, A1,L11,H11)
        INS_BOT(n2,m2,x2, A2,L12,H12) INS_BOT(n3,m3,x3, A3,L13,H13)
        INS_BOT(n4,m4,x4, A4,L14,H14) INS_BOT(n5,m5,x5, A5,L15,H15)
        MERGE(o, n0,m0,x0, n1,m1,x1, n2,m2,x2, n3,m3,x3, n4,m4,x4, n5,m5,x5)
        __builtin_nontemporal_store(o, reinterpret_cast<f32x4*>(out + base));
    }
    {   // row 1: triple (B,C,D) = insert D into (L1,H1)
        INS_TOP(n0,m0,x0, L10,H10,D0) INS_TOP(n1,m1,x1, L11,H11,D1)
        INS_TOP(n2,m2,x2, L12,H12,D2) INS_TOP(n3,m3,x3, L13,H13,D3)
        INS_TOP(n4,m4,x4, L14,H14,D4) INS_TOP(n5,m5,x5, L15,H15,D5)
        MERGE(o, n0,m0,x0, n1,m1,x1, n2,m2,x2, n3,m3,x3, n4,m4,x4, n5,m5,x5)
        __builtin_nontemporal_store(o, reinterpret_cast<f32x4*>(out + base + IMW));
    }
    {   // row 2: triple (C,D,E) = insert C into (L2,H2)
        INS_BOT(n0,m0,x0, C0,L20,H20) INS_BOT(n1,m1,x1, C1,L21,H21)
        INS_BOT(n2,m2,x2, C2,L22,H22) INS_BOT(n3,m3,x3, C3,L23,H23)
        INS_BOT(n4,m4,x4, C4,L24,H24) INS_BOT(n5,m5,x5, C5,L25,H25)
        MERGE(o, n0,m0,x0, n1,m1,x1, n2,m2,x2, n3,m3,x3, n4,m4,x4, n5,m5,x5)
        __builtin_nontemporal_store(o, reinterpret_cast<f32x4*>(out + base + 2 * IMW));
    }
    {   // row 3: triple (D,E,F) = insert F into (L2,H2)
        INS_TOP(n0,m0,x0, L20,H20,F0) INS_TOP(n1,m1,x1, L21,H21,F1)
        INS_TOP(n2,m2,x2, L22,H22,F2) INS_TOP(n3,m3,x3, L23,H23,F3)
        INS_TOP(n4,m4,x4, L24,H24,F4) INS_TOP(n5,m5,x5, L25,H25,F5)
        MERGE(o, n0,m0,x0, n1,m1,x1, n2,m2,x2, n3,m3,x3, n4,m4,x4, n5,m5,x5)
        __builtin_nontemporal_store(o, reinterpret_cast<f32x4*>(out + base + 3 * IMW));
    }
#undef INS_BOT
#undef INS_TOP
#undef MERGE
}

extern "C" void kernel_launch(void* const* d_in, const int* in_sizes, int n_in,
                              void* d_out, int out_size, void* d_ws, size_t ws_size,
                              hipStream_t stream) {
    const float* x = (const float*)d_in[0];
    float* out = (float*)d_out;
    // 12,582,912 px / 16 px-per-thread / 256 = 3072 blocks
    const int blocks = in_sizes[0] / 16 / 256;
    median3_4x4<<<blocks, 256, 0, stream>>>(x, out);
}